// Round 3
// baseline (107.932 us; speedup 1.0000x reference)
//
#include <hip/hip_runtime.h>
#include <hip/hip_cooperative_groups.h>

#define N 4096
#define BLOCK 256
#define JC 64                 // j-chunks
#define JCHUNK (N / JC)       // 64 j's per chunk
#define NB (16 * JC)          // 1024 blocks, 4/CU

namespace cg = cooperative_groups;

// ---- shared per-pair body -------------------------------------------------
template <bool DIAG>
__device__ __forceinline__ void lj_accum(const float* __restrict__ qj, int j0, int i,
                                         float qx, float qy, float qz,
                                         float& fx, float& fy, float& fz) {
    #pragma unroll 8
    for (int jj = 0; jj < JCHUNK; ++jj) {
        const float dx = qx - qj[jj * 3 + 0];   // wave-uniform -> scalar load
        const float dy = qy - qj[jj * 3 + 1];
        const float dz = qz - qj[jj * 3 + 2];
        const float r2 = fmaf(dx, dx, fmaf(dy, dy, dz * dz));
        const float inv_r2  = __builtin_amdgcn_rcpf(r2);   // v_rcp_f32
        const float inv_r4  = inv_r2 * inv_r2;
        const float inv_r8  = inv_r4 * inv_r4;
        const float inv_r14 = inv_r8 * inv_r4 * inv_r2;
        float s = fmaf(-48.0f, inv_r14, 24.0f * inv_r8);   // -48 r^-14 + 24 r^-8
        if (DIAG) s = (j0 + jj == i) ? 0.0f : s;           // predicated
        fx = fmaf(s, dx, fx);
        fy = fmaf(s, dy, fy);
        fz = fmaf(s, dz, fz);
    }
}

// ---- fused cooperative kernel: partials -> grid.sync -> reduce + dq -------
__global__ __launch_bounds__(BLOCK, 4)   // 4 waves/EU -> 4 blocks/CU resident
void lj_fused_kernel(const float* __restrict__ q, const float* __restrict__ p,
                     const float* __restrict__ m, float* __restrict__ out,
                     float* __restrict__ ws) {
    const int bid = blockIdx.x;
    const int bx  = bid & 15;            // i-block (16)
    const int by  = bid >> 4;            // j-chunk (64)
    const int tid = threadIdx.x;

    {   // phase 1: atomic-free partial forces -> ws[by][i][c]
        const int i  = bx * BLOCK + tid;
        const int j0 = by * JCHUNK;
        const float* __restrict__ qj = q + j0 * 3;
        const float qx = q[i*3+0], qy = q[i*3+1], qz = q[i*3+2];
        float fx = 0.f, fy = 0.f, fz = 0.f;
        if ((by >> 2) == bx)             // chunk intersects own i-range
            lj_accum<true >(qj, j0, i, qx, qy, qz, fx, fy, fz);
        else
            lj_accum<false>(qj, j0, i, qx, qy, qz, fx, fy, fz);
        float* w = ws + (size_t)by * (N*3) + i*3;
        w[0] = fx; w[1] = fy; w[2] = fz;
    }

    cg::this_grid().sync();

    if (bid < (N*3) / BLOCK) {           // phase 2: 48 blocks reduce + dq
        const int t = bid * BLOCK + tid; // 0..12287
        float acc = 0.f;
        #pragma unroll 8
        for (int k = 0; k < JC; ++k)
            acc += ws[(size_t)k * (N*3) + t];
        out[N*3 + t] = acc;              // dp
        out[t] = p[t] / m[t/3];          // dq
    }
}

// ---- fallback path (proven R2 kernels) ------------------------------------
__global__ void dq_and_zero_kernel(const float* __restrict__ p,
                                   const float* __restrict__ m,
                                   float* __restrict__ out) {
    int t = blockIdx.x * blockDim.x + threadIdx.x;
    if (t < N * 3) {
        out[t] = p[t] / m[t / 3];
        out[N * 3 + t] = 0.0f;
    }
}

__global__ __launch_bounds__(BLOCK)
void lj_force_kernel(const float* __restrict__ q, float* __restrict__ dp) {
    const int i  = blockIdx.x * BLOCK + threadIdx.x;
    const int j0 = blockIdx.y * JCHUNK;
    const float* __restrict__ qj = q + j0 * 3;
    const float qx = q[i*3+0], qy = q[i*3+1], qz = q[i*3+2];
    float fx = 0.f, fy = 0.f, fz = 0.f;
    if ((blockIdx.y >> 2) == blockIdx.x)
        lj_accum<true >(qj, j0, i, qx, qy, qz, fx, fy, fz);
    else
        lj_accum<false>(qj, j0, i, qx, qy, qz, fx, fy, fz);
    atomicAdd(&dp[i*3+0], fx);
    atomicAdd(&dp[i*3+1], fy);
    atomicAdd(&dp[i*3+2], fz);
}

extern "C" void kernel_launch(void* const* d_in, const int* in_sizes, int n_in,
                              void* d_out, int out_size, void* d_ws, size_t ws_size,
                              hipStream_t stream) {
    const float* q = (const float*)d_in[0];
    const float* p = (const float*)d_in[1];
    const float* m = (const float*)d_in[2];
    float* out = (float*)d_out;
    float* ws  = (float*)d_ws;

    hipError_t e = hipErrorUnknown;
    if (ws_size >= (size_t)JC * N * 3 * sizeof(float)) {
        void* args[] = {(void*)&q, (void*)&p, (void*)&m, (void*)&out, (void*)&ws};
        e = hipLaunchCooperativeKernel((void*)lj_fused_kernel,
                                       dim3(NB), dim3(BLOCK), args, 0, stream);
    }
    if (e != hipSuccess) {   // fallback: proven 2-kernel atomic path
        dq_and_zero_kernel<<<(N * 3 + 255) / 256, 256, 0, stream>>>(p, m, out);
        dim3 grid(N / BLOCK, JC);
        lj_force_kernel<<<grid, BLOCK, 0, stream>>>(q, out + N * 3);
    }
}

// Round 4
// 16.105 us; speedup vs baseline: 6.7017x; 6.7017x over previous
//
#include <hip/hip_runtime.h>

#define N 4096
#define BLOCK 256
#define JC 64                 // j-chunks
#define JCHUNK (N / JC)       // 64 j's per chunk

// ---- per-pair body: wave-uniform j reads -> scalar loads, rcp for 1/r2 ----
template <bool DIAG>
__device__ __forceinline__ void lj_accum(const float* __restrict__ qj, int j0, int i,
                                         float qx, float qy, float qz,
                                         float& fx, float& fy, float& fz) {
    #pragma unroll 8
    for (int jj = 0; jj < JCHUNK; ++jj) {
        const float dx = qx - qj[jj * 3 + 0];   // wave-uniform -> s_load
        const float dy = qy - qj[jj * 3 + 1];
        const float dz = qz - qj[jj * 3 + 2];
        const float r2 = fmaf(dx, dx, fmaf(dy, dy, dz * dz));
        const float inv_r2 = __builtin_amdgcn_rcpf(r2);    // v_rcp_f32
        const float inv_r4 = inv_r2 * inv_r2;
        const float inv_r6 = inv_r4 * inv_r2;
        const float inv_r8 = inv_r4 * inv_r4;
        // -48 r^-14 + 24 r^-8 = r^-8 * (24 - 48 r^-6)
        float s = inv_r8 * fmaf(-48.0f, inv_r6, 24.0f);
        if (DIAG) s = (j0 + jj == i) ? 0.0f : s;           // predicated
        fx = fmaf(s, dx, fx);
        fy = fmaf(s, dy, fy);
        fz = fmaf(s, dz, fz);
    }
}

// ---- kernel A: atomic-free force partials -> ws (SoA) ---------------------
// ws[(by*3 + c)*N + i] = force component c on particle i from j-chunk by.
__global__ __launch_bounds__(BLOCK)
void lj_partial_kernel(const float* __restrict__ q, float* __restrict__ ws) {
    const int bx  = blockIdx.x;          // i-block (16)
    const int by  = blockIdx.y;          // j-chunk (64)
    const int i   = bx * BLOCK + threadIdx.x;
    const int j0  = by * JCHUNK;
    const float* __restrict__ qj = q + j0 * 3;

    const float qx = q[i*3+0], qy = q[i*3+1], qz = q[i*3+2];
    float fx = 0.f, fy = 0.f, fz = 0.f;

    if ((by >> 2) == bx)                 // chunk intersects own i-range
        lj_accum<true >(qj, j0, i, qx, qy, qz, fx, fy, fz);
    else
        lj_accum<false>(qj, j0, i, qx, qy, qz, fx, fy, fz);

    float* w = ws + (size_t)by * 3 * N;
    w[0*N + i] = fx;                     // coalesced SoA stores
    w[1*N + i] = fy;
    w[2*N + i] = fz;
}

// ---- kernel B: reduce partials -> dp, plus dq = p/m ------------------------
__global__ __launch_bounds__(BLOCK)
void lj_reduce_kernel(const float* __restrict__ ws, const float* __restrict__ p,
                      const float* __restrict__ m, float* __restrict__ out) {
    const int u = blockIdx.x * BLOCK + threadIdx.x;   // 0..12287
    // dq (coalesced)
    out[u] = p[u] / m[u / 3];
    // dp: component c of particle i, summed over 64 chunks
    const int c = u >> 12;               // 0..2
    const int i = u & (N - 1);           // 0..4095
    float acc = 0.f;
    #pragma unroll 8
    for (int k = 0; k < JC; ++k)
        acc += ws[((size_t)k * 3 + c) * N + i];       // coalesced per k
    out[N*3 + i*3 + c] = acc;
}

extern "C" void kernel_launch(void* const* d_in, const int* in_sizes, int n_in,
                              void* d_out, int out_size, void* d_ws, size_t ws_size,
                              hipStream_t stream) {
    const float* q = (const float*)d_in[0];
    const float* p = (const float*)d_in[1];
    const float* m = (const float*)d_in[2];
    float* out = (float*)d_out;
    float* ws  = (float*)d_ws;

    dim3 gridA(N / BLOCK, JC);           // 16 x 64 = 1024 blocks
    lj_partial_kernel<<<gridA, BLOCK, 0, stream>>>(q, ws);

    lj_reduce_kernel<<<(N * 3) / BLOCK, BLOCK, 0, stream>>>(ws, p, m, out);
}